// Round 1
// baseline (1892.105 us; speedup 1.0000x reference)
//
#include <hip/hip_runtime.h>
#include <cstdint>
#include <cstddef>

#define NPTS 500000
#define CIN  128
#define GCH  256
#define COUT 128
#define KTAP 27

typedef __attribute__((ext_vector_type(4))) float  f32x4;
typedef __attribute__((ext_vector_type(8))) short  s16x8;

__device__ __forceinline__ unsigned short f2bf(float f) {
  union { float f; uint32_t u; } v; v.f = f;
  uint32_t r = v.u + 0x7FFFu + ((v.u >> 16) & 1u);
  return (unsigned short)(r >> 16);
}
__device__ __forceinline__ float bf2f(unsigned short h) {
  union { uint32_t u; float f; } v; v.u = ((uint32_t)h) << 16;
  return v.f;
}

// ---------- prep: fragment-linear bf16 weights + zero GRN sums ----------
// W1t frag order: gt=(f*4+s)*64+lane holds W1[k0+j][f*16+(lane&15)], k0=s*32+(lane>>4)*8
// W2t frag order: gt=(f*8+s)*64+lane holds W2[k0+j][f*16+(lane&15)]
__global__ __launch_bounds__(256) void k_prep(
    const float* __restrict__ W1, const float* __restrict__ W2,
    unsigned short* __restrict__ W1t, unsigned short* __restrict__ W2t,
    float* __restrict__ sums) {
  int b = blockIdx.x, t = threadIdx.x;
  if (b == 0 && t < COUT) sums[t] = 0.f;
  int gt = (b & 15) * 256 + t;      // 0..4095
  int grp = gt >> 6, lane = gt & 63;
  int l15 = lane & 15, l4 = lane >> 4;
  if (b < 16) {
    int f = grp >> 2, s = grp & 3;
    int col = f * 16 + l15, k0 = s * 32 + l4 * 8;
    unsigned short* dst = W1t + gt * 8;
#pragma unroll
    for (int j = 0; j < 8; ++j) dst[j] = f2bf(W1[(size_t)(k0 + j) * GCH + col]);
  } else {
    int f = grp >> 3, s = grp & 7;
    int col = f * 16 + l15, k0 = s * 32 + l4 * 8;
    unsigned short* dst = W2t + gt * 8;
#pragma unroll
    for (int j = 0; j < 8; ++j) dst[j] = f2bf(W2[(size_t)(k0 + j) * COUT + col]);
  }
}

// ---------- K1: h1 = LN(x @ W1 + b1) -> bf16 [N][256] ----------
__global__ __launch_bounds__(512) void k_gemm1_ln(
    const float* __restrict__ x, const unsigned short* __restrict__ W1t,
    const float* __restrict__ b1, const float* __restrict__ ln_g,
    const float* __restrict__ ln_b, unsigned short* __restrict__ h1) {
  __shared__ unsigned short Al[128][CIN + 8];   // 34.8 KB, +8 pad vs bank conflicts
  __shared__ unsigned short Bl[GCH * CIN];      // 64 KB frag-linear
  int tid = threadIdx.x, lane = tid & 63, wv = tid >> 6;
  int l15 = lane & 15, l4 = lane >> 4;
  long rowbase = (long)blockIdx.x * 128;

#pragma unroll
  for (int i = 0; i < 8; ++i) {                 // stage B
    int off = (i * 512 + tid) * 8;
    *(s16x8*)&Bl[off] = *(const s16x8*)&W1t[off];
  }
  {                                             // stage A (fp32 -> bf16)
    int ar = tid >> 2, ac = (tid & 3) * 32;
    long gr = rowbase + ar;
    const float* xp = x + gr * CIN + ac;
    bool ok = gr < NPTS;
#pragma unroll
    for (int u = 0; u < 8; ++u) {
      f32x4 v = {0.f, 0.f, 0.f, 0.f};
      if (ok) v = *(const f32x4*)(xp + u * 4);
      unsigned short* d = &Al[ar][ac + u * 4];
      d[0] = f2bf(v[0]); d[1] = f2bf(v[1]); d[2] = f2bf(v[2]); d[3] = f2bf(v[3]);
    }
  }
  __syncthreads();

  f32x4 acc[16];
#pragma unroll
  for (int f = 0; f < 16; ++f) acc[f] = (f32x4){0.f, 0.f, 0.f, 0.f};
  s16x8 a[4];
#pragma unroll
  for (int s = 0; s < 4; ++s)
    a[s] = *(const s16x8*)&Al[wv * 16 + l15][s * 32 + l4 * 8];
#pragma unroll
  for (int f = 0; f < 16; ++f)
#pragma unroll
    for (int s = 0; s < 4; ++s) {
      s16x8 bfr = *(const s16x8*)&Bl[((f * 4 + s) * 64 + lane) * 8];
      acc[f] = __builtin_amdgcn_mfma_f32_16x16x32_bf16(a[s], bfr, acc[f], 0, 0, 0);
    }

  // + b1, LN over 256 channels (rows live in 16-lane groups x 16 frags)
  float s1[4] = {0, 0, 0, 0}, s2[4] = {0, 0, 0, 0};
#pragma unroll
  for (int f = 0; f < 16; ++f) {
    float bb = b1[f * 16 + l15];
#pragma unroll
    for (int j = 0; j < 4; ++j) {
      float v = acc[f][j] + bb;
      acc[f][j] = v;
      s1[j] += v; s2[j] += v * v;
    }
  }
#pragma unroll
  for (int m = 1; m < 16; m <<= 1)
#pragma unroll
    for (int j = 0; j < 4; ++j) {
      s1[j] += __shfl_xor(s1[j], m);
      s2[j] += __shfl_xor(s2[j], m);
    }
  float mu[4], rs[4];
#pragma unroll
  for (int j = 0; j < 4; ++j) {
    mu[j] = s1[j] * (1.f / GCH);
    float var = s2[j] * (1.f / GCH) - mu[j] * mu[j];
    rs[j] = rsqrtf(var + 1e-6f);
  }
#pragma unroll
  for (int f = 0; f < 16; ++f) {
    int col = f * 16 + l15;
    float g = ln_g[col], bta = ln_b[col];
#pragma unroll
    for (int j = 0; j < 4; ++j) {
      long r = rowbase + wv * 16 + l4 * 4 + j;
      if (r < NPTS) {
        float v = (acc[f][j] - mu[j]) * rs[j] * g + bta;
        h1[r * GCH + col] = f2bf(v);
      }
    }
  }
}

// ---------- K2: depthwise gather, h2 = sum_k h1[nbr[k]]*dw_w[k] + dw_b ----------
__global__ __launch_bounds__(256) void k_dw(
    const unsigned short* __restrict__ h1, const int* __restrict__ nbr,
    const float* __restrict__ dw_w, const float* __restrict__ dw_b,
    unsigned short* __restrict__ h2) {
  __shared__ unsigned short wl[KTAP][GCH];      // 13.8 KB bf16 weights
  int tid = threadIdx.x, lane = tid & 63, wv = tid >> 6;
  for (int i = tid; i < KTAP * GCH; i += 256)
    ((unsigned short*)wl)[i] = f2bf(dw_w[i]);
  __syncthreads();
  int c0 = lane * 4;
  f32x4 bias = *(const f32x4*)(dw_b + c0);
  int pbase = (blockIdx.x * 4 + wv) * 4;        // 4 points per wave
#pragma unroll
  for (int pp = 0; pp < 4; ++pp) {
    int p = __builtin_amdgcn_readfirstlane(pbase + pp);
    const int* rp = nbr + (size_t)p * KTAP;
    int rows[KTAP];
#pragma unroll
    for (int k = 0; k < KTAP; ++k) rows[k] = rp[k];   // uniform -> s_loads
    f32x4 acc = bias;
#pragma unroll
    for (int k = 0; k < KTAP; ++k) {
      const unsigned short* sp = h1 + (size_t)rows[k] * GCH + c0;
      ushort4 hv = *(const ushort4*)sp;               // 8B per lane, 512B/row coalesced
      ushort4 wq = *(const ushort4*)&wl[k][c0];
      acc[0] += bf2f(hv.x) * bf2f(wq.x);
      acc[1] += bf2f(hv.y) * bf2f(wq.y);
      acc[2] += bf2f(hv.z) * bf2f(wq.z);
      acc[3] += bf2f(hv.w) * bf2f(wq.w);
    }
    ushort4 o;
    o.x = f2bf(acc[0]); o.y = f2bf(acc[1]); o.z = f2bf(acc[2]); o.w = f2bf(acc[3]);
    *(ushort4*)(h2 + (size_t)p * GCH + c0) = o;
  }
}

// ---------- K4: h3 = gelu(h2 @ W2 + b2) bf16, + per-channel sum(h3^2) ----------
__global__ __launch_bounds__(512) void k_gemm2(
    const unsigned short* __restrict__ h2, const unsigned short* __restrict__ W2t,
    const float* __restrict__ b2, unsigned short* __restrict__ h3,
    float* __restrict__ sums) {
  __shared__ unsigned short Al[128][GCH + 8];   // 67.6 KB
  __shared__ unsigned short Bl[COUT * GCH];     // 64 KB
  __shared__ float ssum[COUT];
  int tid = threadIdx.x, lane = tid & 63, wv = tid >> 6;
  int l15 = lane & 15, l4 = lane >> 4;
  long rowbase = (long)blockIdx.x * 128;
  if (tid < COUT) ssum[tid] = 0.f;
#pragma unroll
  for (int i = 0; i < 8; ++i) {
    int off = (i * 512 + tid) * 8;
    *(s16x8*)&Bl[off] = *(const s16x8*)&W2t[off];
  }
  {
    int ar = tid >> 2, ac = (tid & 3) * 64;
    long gr = rowbase + ar;
    const unsigned short* sp = h2 + gr * GCH + ac;
    bool ok = gr < NPTS;
    s16x8 zs = {0, 0, 0, 0, 0, 0, 0, 0};
#pragma unroll
    for (int u = 0; u < 8; ++u) {
      s16x8 v = zs;
      if (ok) v = *(const s16x8*)(sp + u * 8);
      *(s16x8*)&Al[ar][ac + u * 8] = v;
    }
  }
  __syncthreads();

  f32x4 acc[8];
#pragma unroll
  for (int f = 0; f < 8; ++f) acc[f] = (f32x4){0.f, 0.f, 0.f, 0.f};
  s16x8 a[8];
#pragma unroll
  for (int s = 0; s < 8; ++s)
    a[s] = *(const s16x8*)&Al[wv * 16 + l15][s * 32 + l4 * 8];
#pragma unroll
  for (int f = 0; f < 8; ++f)
#pragma unroll
    for (int s = 0; s < 8; ++s) {
      s16x8 bfr = *(const s16x8*)&Bl[((f * 8 + s) * 64 + lane) * 8];
      acc[f] = __builtin_amdgcn_mfma_f32_16x16x32_bf16(a[s], bfr, acc[f], 0, 0, 0);
    }
#pragma unroll
  for (int f = 0; f < 8; ++f) {
    int col = f * 16 + l15;
    float bb = b2[col];
    float ps = 0.f;
#pragma unroll
    for (int j = 0; j < 4; ++j) {
      long r = rowbase + wv * 16 + l4 * 4 + j;
      float v = acc[f][j] + bb;
      float g = 0.5f * v * (1.f + erff(v * 0.70710678118654752f));
      if (r < NPTS) {
        h3[r * COUT + col] = f2bf(g);
        ps += g * g;
      }
    }
    ps += __shfl_xor(ps, 16);
    ps += __shfl_xor(ps, 32);
    if (l4 == 0) atomicAdd(&ssum[col], ps);
  }
  __syncthreads();
  if (tid < COUT) atomicAdd(&sums[tid], ssum[tid]);
}

// ---------- K5: GRN finalize -> scale/shift tables ----------
__global__ void k_grn(const float* __restrict__ sums, const float* __restrict__ grn_g,
                      const float* __restrict__ grn_b, float* __restrict__ sAB) {
  __shared__ float gx[COUT];
  __shared__ float mean_s;
  int t = threadIdx.x;
  float g = sqrtf(sums[t]);
  gx[t] = g;
  __syncthreads();
  if (t == 0) {
    float s = 0.f;
    for (int i = 0; i < COUT; ++i) s += gx[i];
    mean_s = s * (1.f / COUT);
  }
  __syncthreads();
  float nx = g / (mean_s + 1e-6f);
  sAB[t] = grn_g[t] * nx + 1.f;   // out = h3*(grn_g*Nx + 1) + grn_b + x
  sAB[COUT + t] = grn_b[t];
}

// ---------- K6: out = h3*sA + sB + x ----------
__global__ __launch_bounds__(256) void k_final(
    const unsigned short* __restrict__ h3, const float* __restrict__ x,
    const float* __restrict__ sAB, float* __restrict__ out) {
  long q = (long)blockIdx.x * 256 + threadIdx.x;
  long idx = q * 4;
  int c0 = (int)(idx & (COUT - 1));
  f32x4 sA = *(const f32x4*)(sAB + c0);
  f32x4 sB = *(const f32x4*)(sAB + COUT + c0);
  ushort4 hv = *(const ushort4*)(h3 + idx);
  f32x4 xv = *(const f32x4*)(x + idx);
  f32x4 r;
  r[0] = bf2f(hv.x) * sA[0] + sB[0] + xv[0];
  r[1] = bf2f(hv.y) * sA[1] + sB[1] + xv[1];
  r[2] = bf2f(hv.z) * sA[2] + sB[2] + xv[2];
  r[3] = bf2f(hv.w) * sA[3] + sB[3] + xv[3];
  *(f32x4*)(out + idx) = r;
}

extern "C" void kernel_launch(void* const* d_in, const int* in_sizes, int n_in,
                              void* d_out, int out_size, void* d_ws, size_t ws_size,
                              hipStream_t stream) {
  const float* x     = (const float*)d_in[0];
  const int*   nbr   = (const int*)d_in[1];
  const float* W1    = (const float*)d_in[2];
  const float* b1    = (const float*)d_in[3];
  const float* ln_g  = (const float*)d_in[4];
  const float* ln_b  = (const float*)d_in[5];
  const float* dw_w  = (const float*)d_in[6];
  const float* dw_b  = (const float*)d_in[7];
  const float* W2    = (const float*)d_in[8];
  const float* b2    = (const float*)d_in[9];
  const float* grn_g = (const float*)d_in[10];
  const float* grn_b = (const float*)d_in[11];
  float* out = (float*)d_out;

  char* ws = (char*)d_ws;
  unsigned short* h1  = (unsigned short*)ws;                 // [N][256] bf16, 256 MB
  size_t off = (size_t)NPTS * GCH * 2;
  unsigned short* W1t = (unsigned short*)(ws + off);         // 64 KB
  unsigned short* W2t = (unsigned short*)(ws + off + 65536); // 64 KB
  float* sums         = (float*)(ws + off + 131072);         // 512 B
  float* sAB          = (float*)(ws + off + 131072 + 512);   // 1 KB
  unsigned short* h2  = (unsigned short*)d_out;              // [N][256] bf16 aliases d_out
  unsigned short* h3  = h1;                                  // [N][128] bf16 reuses h1

  k_prep<<<32, 256, 0, stream>>>(W1, W2, W1t, W2t, sums);
  k_gemm1_ln<<<(NPTS + 127) / 128, 512, 0, stream>>>(x, W1t, b1, ln_g, ln_b, h1);
  k_dw<<<NPTS / 16, 256, 0, stream>>>(h1, nbr, dw_w, dw_b, h2);
  k_gemm2<<<(NPTS + 127) / 128, 512, 0, stream>>>(h2, W2t, b2, h3, sums);
  k_grn<<<1, COUT, 0, stream>>>(sums, grn_g, grn_b, sAB);
  k_final<<<(NPTS * COUT / 4) / 256, 256, 0, stream>>>(h3, x, sAB, out);
}

// Round 2
// 1724.953 us; speedup vs baseline: 1.0969x; 1.0969x over previous
//
#include <hip/hip_runtime.h>
#include <cstdint>
#include <cstddef>

#define NPTS 500000
#define CIN  128
#define GCH  256
#define COUT 128
#define KTAP 27

typedef __attribute__((ext_vector_type(4))) float    f32x4;
typedef __attribute__((ext_vector_type(8))) short    s16x8;
typedef __attribute__((ext_vector_type(4))) uint32_t u32x4;

__device__ __forceinline__ unsigned short f2bf(float f) {
  union { float f; uint32_t u; } v; v.f = f;
  uint32_t r = v.u + 0x7FFFu + ((v.u >> 16) & 1u);
  return (unsigned short)(r >> 16);
}
__device__ __forceinline__ float bf2f(unsigned short h) {
  union { uint32_t u; float f; } v; v.u = ((uint32_t)h) << 16;
  return v.f;
}
__device__ __forceinline__ float bflo(uint32_t u) {
  union { uint32_t u; float f; } v; v.u = u << 16; return v.f;
}
__device__ __forceinline__ float bfhi(uint32_t u) {
  union { uint32_t u; float f; } v; v.u = u & 0xFFFF0000u; return v.f;
}

// ---------- prep: fragment-linear bf16 weights + zero GRN sums ----------
__global__ __launch_bounds__(256) void k_prep(
    const float* __restrict__ W1, const float* __restrict__ W2,
    unsigned short* __restrict__ W1t, unsigned short* __restrict__ W2t,
    float* __restrict__ sums) {
  int b = blockIdx.x, t = threadIdx.x;
  if (b == 0 && t < COUT) sums[t] = 0.f;
  int gt = (b & 15) * 256 + t;      // 0..4095
  int grp = gt >> 6, lane = gt & 63;
  int l15 = lane & 15, l4 = lane >> 4;
  if (b < 16) {
    int f = grp >> 2, s = grp & 3;
    int col = f * 16 + l15, k0 = s * 32 + l4 * 8;
    unsigned short* dst = W1t + gt * 8;
#pragma unroll
    for (int j = 0; j < 8; ++j) dst[j] = f2bf(W1[(size_t)(k0 + j) * GCH + col]);
  } else {
    int f = grp >> 3, s = grp & 7;
    int col = f * 16 + l15, k0 = s * 32 + l4 * 8;
    unsigned short* dst = W2t + gt * 8;
#pragma unroll
    for (int j = 0; j < 8; ++j) dst[j] = f2bf(W2[(size_t)(k0 + j) * COUT + col]);
  }
}

// ---------- K1: h1 = LN(x @ W1 + b1) -> bf16 [N][256] ----------
__global__ __launch_bounds__(512) void k_gemm1_ln(
    const float* __restrict__ x, const unsigned short* __restrict__ W1t,
    const float* __restrict__ b1, const float* __restrict__ ln_g,
    const float* __restrict__ ln_b, unsigned short* __restrict__ h1) {
  __shared__ unsigned short Al[128][CIN + 8];
  __shared__ unsigned short Bl[GCH * CIN];
  int tid = threadIdx.x, lane = tid & 63, wv = tid >> 6;
  int l15 = lane & 15, l4 = lane >> 4;
  long rowbase = (long)blockIdx.x * 128;

#pragma unroll
  for (int i = 0; i < 8; ++i) {                 // stage B
    int off = (i * 512 + tid) * 8;
    *(s16x8*)&Bl[off] = *(const s16x8*)&W1t[off];
  }
  {                                             // stage A (fp32 -> bf16), nt: x is read-once here
    int ar = tid >> 2, ac = (tid & 3) * 32;
    long gr = rowbase + ar;
    const float* xp = x + gr * CIN + ac;
    bool ok = gr < NPTS;
#pragma unroll
    for (int u = 0; u < 8; ++u) {
      f32x4 v = {0.f, 0.f, 0.f, 0.f};
      if (ok) v = __builtin_nontemporal_load((const f32x4*)(xp + u * 4));
      unsigned short* d = &Al[ar][ac + u * 4];
      d[0] = f2bf(v[0]); d[1] = f2bf(v[1]); d[2] = f2bf(v[2]); d[3] = f2bf(v[3]);
    }
  }
  __syncthreads();

  f32x4 acc[16];
#pragma unroll
  for (int f = 0; f < 16; ++f) acc[f] = (f32x4){0.f, 0.f, 0.f, 0.f};
  s16x8 a[4];
#pragma unroll
  for (int s = 0; s < 4; ++s)
    a[s] = *(const s16x8*)&Al[wv * 16 + l15][s * 32 + l4 * 8];
#pragma unroll
  for (int f = 0; f < 16; ++f)
#pragma unroll
    for (int s = 0; s < 4; ++s) {
      s16x8 bfr = *(const s16x8*)&Bl[((f * 4 + s) * 64 + lane) * 8];
      acc[f] = __builtin_amdgcn_mfma_f32_16x16x32_bf16(a[s], bfr, acc[f], 0, 0, 0);
    }

  float s1[4] = {0, 0, 0, 0}, s2[4] = {0, 0, 0, 0};
#pragma unroll
  for (int f = 0; f < 16; ++f) {
    float bb = b1[f * 16 + l15];
#pragma unroll
    for (int j = 0; j < 4; ++j) {
      float v = acc[f][j] + bb;
      acc[f][j] = v;
      s1[j] += v; s2[j] += v * v;
    }
  }
#pragma unroll
  for (int m = 1; m < 16; m <<= 1)
#pragma unroll
    for (int j = 0; j < 4; ++j) {
      s1[j] += __shfl_xor(s1[j], m);
      s2[j] += __shfl_xor(s2[j], m);
    }
  float mu[4], rs[4];
#pragma unroll
  for (int j = 0; j < 4; ++j) {
    mu[j] = s1[j] * (1.f / GCH);
    float var = s2[j] * (1.f / GCH) - mu[j] * mu[j];
    rs[j] = rsqrtf(var + 1e-6f);
  }
#pragma unroll
  for (int f = 0; f < 16; ++f) {
    int col = f * 16 + l15;
    float g = ln_g[col], bta = ln_b[col];
#pragma unroll
    for (int j = 0; j < 4; ++j) {
      long r = rowbase + wv * 16 + l4 * 4 + j;
      if (r < NPTS) {
        float v = (acc[f][j] - mu[j]) * rs[j] * g + bta;
        h1[r * GCH + col] = f2bf(v);   // normal store: want h1 L3-resident for gather
      }
    }
  }
}

// ---------- K2: depthwise gather, 2 points per wave (half-wave split, 16B loads) ----------
__global__ __launch_bounds__(256) void k_dw(
    const unsigned short* __restrict__ h1, const int* __restrict__ nbr,
    const float* __restrict__ dw_w, const float* __restrict__ dw_b,
    unsigned short* __restrict__ h2) {
  __shared__ unsigned short wl[KTAP][GCH];      // 13.8 KB bf16 weights
  int tid = threadIdx.x, lane = tid & 63, wv = tid >> 6;
  for (int i = tid; i < KTAP * GCH; i += 256)
    ((unsigned short*)wl)[i] = f2bf(dw_w[i]);
  __syncthreads();

  int li = lane & 31;
  int c0 = li * 8;                              // 8 channels per lane
  bool hi = lane >= 32;
  f32x4 b0 = *(const f32x4*)(dw_b + c0);
  f32x4 b1v = *(const f32x4*)(dw_b + c0 + 4);
  const char* h1c = (const char*)h1;
  int pbase = blockIdx.x * 16 + wv * 4;         // 4 points per wave (2 pairs)

#pragma unroll
  for (int pp = 0; pp < 2; ++pp) {
    int pA = __builtin_amdgcn_readfirstlane(pbase + pp * 2);
    const int* rpA = nbr + (size_t)pA * KTAP;
    int rA[KTAP], rB[KTAP];
#pragma unroll
    for (int k = 0; k < KTAP; ++k) { rA[k] = rpA[k]; rB[k] = rpA[KTAP + k]; }

    float acc[8];
    acc[0] = b0[0]; acc[1] = b0[1]; acc[2] = b0[2]; acc[3] = b0[3];
    acc[4] = b1v[0]; acc[5] = b1v[1]; acc[6] = b1v[2]; acc[7] = b1v[3];

#pragma unroll
    for (int k = 0; k < KTAP; ++k) {
      int row = hi ? rB[k] : rA[k];
      uint32_t boff = ((uint32_t)row << 9) + (uint32_t)(c0 * 2);
      u32x4 hv = *(const u32x4*)(h1c + boff);           // 16B/lane, full 512B row per half-wave
      u32x4 wq = *(const u32x4*)&wl[k][c0];             // broadcast across halves
#pragma unroll
      for (int d = 0; d < 4; ++d) {
        acc[2 * d]     += bflo(hv[d]) * bflo(wq[d]);
        acc[2 * d + 1] += bfhi(hv[d]) * bfhi(wq[d]);
      }
    }
    u32x4 ov;
#pragma unroll
    for (int d = 0; d < 4; ++d)
      ov[d] = (uint32_t)f2bf(acc[2 * d]) | ((uint32_t)f2bf(acc[2 * d + 1]) << 16);
    int p = pbase + pp * 2 + (hi ? 1 : 0);
    __builtin_nontemporal_store(ov, (u32x4*)(h2 + (size_t)p * GCH + c0));  // nt: don't evict h1
  }
}

// ---------- K4: h3 = gelu(h2 @ W2 + b2) bf16, + per-channel sum(h3^2) ----------
__global__ __launch_bounds__(512) void k_gemm2(
    const unsigned short* __restrict__ h2, const unsigned short* __restrict__ W2t,
    const float* __restrict__ b2, unsigned short* __restrict__ h3,
    float* __restrict__ sums) {
  __shared__ unsigned short Al[128][GCH + 8];
  __shared__ unsigned short Bl[COUT * GCH];
  __shared__ float ssum[COUT];
  int tid = threadIdx.x, lane = tid & 63, wv = tid >> 6;
  int l15 = lane & 15, l4 = lane >> 4;
  long rowbase = (long)blockIdx.x * 128;
  if (tid < COUT) ssum[tid] = 0.f;
#pragma unroll
  for (int i = 0; i < 8; ++i) {
    int off = (i * 512 + tid) * 8;
    *(s16x8*)&Bl[off] = *(const s16x8*)&W2t[off];
  }
  {
    int ar = tid >> 2, ac = (tid & 3) * 64;
    long gr = rowbase + ar;
    const unsigned short* sp = h2 + gr * GCH + ac;
    bool ok = gr < NPTS;
    s16x8 zs = {0, 0, 0, 0, 0, 0, 0, 0};
#pragma unroll
    for (int u = 0; u < 8; ++u) {
      s16x8 v = zs;
      if (ok) v = __builtin_nontemporal_load((const s16x8*)(sp + u * 8));  // h2 read-once
      *(s16x8*)&Al[ar][ac + u * 8] = v;
    }
  }
  __syncthreads();

  f32x4 acc[8];
#pragma unroll
  for (int f = 0; f < 8; ++f) acc[f] = (f32x4){0.f, 0.f, 0.f, 0.f};
  s16x8 a[8];
#pragma unroll
  for (int s = 0; s < 8; ++s)
    a[s] = *(const s16x8*)&Al[wv * 16 + l15][s * 32 + l4 * 8];
#pragma unroll
  for (int f = 0; f < 8; ++f)
#pragma unroll
    for (int s = 0; s < 8; ++s) {
      s16x8 bfr = *(const s16x8*)&Bl[((f * 8 + s) * 64 + lane) * 8];
      acc[f] = __builtin_amdgcn_mfma_f32_16x16x32_bf16(a[s], bfr, acc[f], 0, 0, 0);
    }
#pragma unroll
  for (int f = 0; f < 8; ++f) {
    int col = f * 16 + l15;
    float bb = b2[col];
    float ps = 0.f;
#pragma unroll
    for (int j = 0; j < 4; ++j) {
      long r = rowbase + wv * 16 + l4 * 4 + j;
      float v = acc[f][j] + bb;
      float g = 0.5f * v * (1.f + erff(v * 0.70710678118654752f));
      if (r < NPTS) {
        h3[r * COUT + col] = f2bf(g);
        ps += g * g;
      }
    }
    ps += __shfl_xor(ps, 16);
    ps += __shfl_xor(ps, 32);
    if (l4 == 0) atomicAdd(&ssum[col], ps);
  }
  __syncthreads();
  if (tid < COUT) atomicAdd(&sums[tid], ssum[tid]);
}

// ---------- K5: GRN finalize -> scale/shift tables ----------
__global__ void k_grn(const float* __restrict__ sums, const float* __restrict__ grn_g,
                      const float* __restrict__ grn_b, float* __restrict__ sAB) {
  __shared__ float gx[COUT];
  __shared__ float mean_s;
  int t = threadIdx.x;
  float g = sqrtf(sums[t]);
  gx[t] = g;
  __syncthreads();
  if (t == 0) {
    float s = 0.f;
    for (int i = 0; i < COUT; ++i) s += gx[i];
    mean_s = s * (1.f / COUT);
  }
  __syncthreads();
  float nx = g / (mean_s + 1e-6f);
  sAB[t] = grn_g[t] * nx + 1.f;
  sAB[COUT + t] = grn_b[t];
}

// ---------- K6: out = h3*sA + sB + x ----------
__global__ __launch_bounds__(256) void k_final(
    const unsigned short* __restrict__ h3, const float* __restrict__ x,
    const float* __restrict__ sAB, float* __restrict__ out) {
  long q = (long)blockIdx.x * 256 + threadIdx.x;
  long idx = q * 4;
  int c0 = (int)(idx & (COUT - 1));
  f32x4 sA = *(const f32x4*)(sAB + c0);
  f32x4 sB = *(const f32x4*)(sAB + COUT + c0);
  ushort4 hv = *(const ushort4*)(h3 + idx);
  f32x4 xv = __builtin_nontemporal_load((const f32x4*)(x + idx));
  f32x4 r;
  r[0] = bf2f(hv.x) * sA[0] + sB[0] + xv[0];
  r[1] = bf2f(hv.y) * sA[1] + sB[1] + xv[1];
  r[2] = bf2f(hv.z) * sA[2] + sB[2] + xv[2];
  r[3] = bf2f(hv.w) * sA[3] + sB[3] + xv[3];
  __builtin_nontemporal_store(r, (f32x4*)(out + idx));
}

extern "C" void kernel_launch(void* const* d_in, const int* in_sizes, int n_in,
                              void* d_out, int out_size, void* d_ws, size_t ws_size,
                              hipStream_t stream) {
  const float* x     = (const float*)d_in[0];
  const int*   nbr   = (const int*)d_in[1];
  const float* W1    = (const float*)d_in[2];
  const float* b1    = (const float*)d_in[3];
  const float* ln_g  = (const float*)d_in[4];
  const float* ln_b  = (const float*)d_in[5];
  const float* dw_w  = (const float*)d_in[6];
  const float* dw_b  = (const float*)d_in[7];
  const float* W2    = (const float*)d_in[8];
  const float* b2    = (const float*)d_in[9];
  const float* grn_g = (const float*)d_in[10];
  const float* grn_b = (const float*)d_in[11];
  float* out = (float*)d_out;

  char* ws = (char*)d_ws;
  unsigned short* h1  = (unsigned short*)ws;                 // [N][256] bf16, 256 MB
  size_t off = (size_t)NPTS * GCH * 2;
  unsigned short* W1t = (unsigned short*)(ws + off);
  unsigned short* W2t = (unsigned short*)(ws + off + 65536);
  float* sums         = (float*)(ws + off + 131072);
  float* sAB          = (float*)(ws + off + 131072 + 512);
  unsigned short* h2  = (unsigned short*)d_out;              // bf16 aliases d_out
  unsigned short* h3  = h1;                                  // reuses h1

  k_prep<<<32, 256, 0, stream>>>(W1, W2, W1t, W2t, sums);
  k_gemm1_ln<<<(NPTS + 127) / 128, 512, 0, stream>>>(x, W1t, b1, ln_g, ln_b, h1);
  k_dw<<<NPTS / 16, 256, 0, stream>>>(h1, nbr, dw_w, dw_b, h2);
  k_gemm2<<<(NPTS + 127) / 128, 512, 0, stream>>>(h2, W2t, b2, h3, sums);
  k_grn<<<1, COUT, 0, stream>>>(sums, grn_g, grn_b, sAB);
  k_final<<<(NPTS * COUT / 4) / 256, 256, 0, stream>>>(h3, x, sAB, out);
}

// Round 3
// 1187.173 us; speedup vs baseline: 1.5938x; 1.4530x over previous
//
#include <hip/hip_runtime.h>
#include <cstdint>
#include <cstddef>

#define NPTS 500000
#define CIN  128
#define GCH  256
#define COUT 128
#define KTAP 27

typedef __attribute__((ext_vector_type(4))) float    f32x4;
typedef __attribute__((ext_vector_type(2))) float    f32x2;
typedef __attribute__((ext_vector_type(8))) short    s16x8;
typedef __attribute__((ext_vector_type(4))) uint32_t u32x4;

__device__ __forceinline__ unsigned short f2bf(float f) {
  union { float f; uint32_t u; } v; v.f = f;
  uint32_t r = v.u + 0x7FFFu + ((v.u >> 16) & 1u);
  return (unsigned short)(r >> 16);
}
__device__ __forceinline__ float bf2f(unsigned short h) {
  union { uint32_t u; float f; } v; v.u = ((uint32_t)h) << 16;
  return v.f;
}

// ---------- prep: fragment-linear bf16 weights + zero GRN sums ----------
__global__ __launch_bounds__(256) void k_prep(
    const float* __restrict__ W1, const float* __restrict__ W2,
    unsigned short* __restrict__ W1t, unsigned short* __restrict__ W2t,
    float* __restrict__ sums) {
  int b = blockIdx.x, t = threadIdx.x;
  if (b == 0 && t < COUT) sums[t] = 0.f;
  int gt = (b & 15) * 256 + t;      // 0..4095
  int grp = gt >> 6, lane = gt & 63;
  int l15 = lane & 15, l4 = lane >> 4;
  if (b < 16) {
    int f = grp >> 2, s = grp & 3;
    int col = f * 16 + l15, k0 = s * 32 + l4 * 8;
    unsigned short* dst = W1t + gt * 8;
#pragma unroll
    for (int j = 0; j < 8; ++j) dst[j] = f2bf(W1[(size_t)(k0 + j) * GCH + col]);
  } else {
    int f = grp >> 3, s = grp & 7;
    int col = f * 16 + l15, k0 = s * 32 + l4 * 8;
    unsigned short* dst = W2t + gt * 8;
#pragma unroll
    for (int j = 0; j < 8; ++j) dst[j] = f2bf(W2[(size_t)(k0 + j) * COUT + col]);
  }
}

// ---------- K1: h1 = LN(x @ W1 + b1) -> fp8 e4m3 [N][256] (LDS transpose, coalesced) ----------
__global__ __launch_bounds__(512) void k_gemm1_ln(
    const float* __restrict__ x, const unsigned short* __restrict__ W1t,
    const float* __restrict__ b1, const float* __restrict__ ln_g,
    const float* __restrict__ ln_b, uint8_t* __restrict__ h1f8) {
  __shared__ char smem_c[100352];
  unsigned short (*Al)[CIN + 8] = (unsigned short (*)[CIN + 8])smem_c;  // 34816 B
  unsigned short* Bl = (unsigned short*)(smem_c + 34816);               // 65536 B
  int tid = threadIdx.x, lane = tid & 63, wv = tid >> 6;
  int l15 = lane & 15, l4 = lane >> 4;
  long rowbase = (long)blockIdx.x * 128;

#pragma unroll
  for (int i = 0; i < 8; ++i) {                 // stage B (frag-linear)
    int off = (i * 512 + tid) * 8;
    *(s16x8*)&Bl[off] = *(const s16x8*)&W1t[off];
  }
  {                                             // stage A (fp32 -> bf16), x read-once
    int ar = tid >> 2, ac = (tid & 3) * 32;
    long gr = rowbase + ar;
    const float* xp = x + gr * CIN + ac;
    bool ok = gr < NPTS;
#pragma unroll
    for (int u = 0; u < 8; ++u) {
      f32x4 v = {0.f, 0.f, 0.f, 0.f};
      if (ok) v = __builtin_nontemporal_load((const f32x4*)(xp + u * 4));
      unsigned short* d = &Al[ar][ac + u * 4];
      d[0] = f2bf(v[0]); d[1] = f2bf(v[1]); d[2] = f2bf(v[2]); d[3] = f2bf(v[3]);
    }
  }
  __syncthreads();

  f32x4 acc[16];
#pragma unroll
  for (int f = 0; f < 16; ++f) acc[f] = (f32x4){0.f, 0.f, 0.f, 0.f};
  s16x8 a[4];
#pragma unroll
  for (int s = 0; s < 4; ++s)
    a[s] = *(const s16x8*)&Al[wv * 16 + l15][s * 32 + l4 * 8];
#pragma unroll
  for (int f = 0; f < 16; ++f)
#pragma unroll
    for (int s = 0; s < 4; ++s) {
      s16x8 bfr = *(const s16x8*)&Bl[((f * 4 + s) * 64 + lane) * 8];
      acc[f] = __builtin_amdgcn_mfma_f32_16x16x32_bf16(a[s], bfr, acc[f], 0, 0, 0);
    }

  float s1[4] = {0, 0, 0, 0}, s2[4] = {0, 0, 0, 0};
#pragma unroll
  for (int f = 0; f < 16; ++f) {
    float bb = b1[f * 16 + l15];
#pragma unroll
    for (int j = 0; j < 4; ++j) {
      float v = acc[f][j] + bb;
      acc[f][j] = v;
      s1[j] += v; s2[j] += v * v;
    }
  }
#pragma unroll
  for (int m = 1; m < 16; m <<= 1)
#pragma unroll
    for (int j = 0; j < 4; ++j) {
      s1[j] += __shfl_xor(s1[j], m);
      s2[j] += __shfl_xor(s2[j], m);
    }
  float mu[4], rs[4];
#pragma unroll
  for (int j = 0; j < 4; ++j) {
    mu[j] = s1[j] * (1.f / GCH);
    float var = s2[j] * (1.f / GCH) - mu[j] * mu[j];
    rs[j] = rsqrtf(var + 1e-6f);
  }

  __syncthreads();   // everyone done reading Al/Bl -> reuse as bf16 tile [128][256], XOR-swizzled
#pragma unroll
  for (int f = 0; f < 16; ++f) {
    int col = f * 16 + l15;
    float g = ln_g[col], bta = ln_b[col];
#pragma unroll
    for (int j = 0; j < 4; ++j) {
      int r = wv * 16 + l4 * 4 + j;
      float v = (acc[f][j] - mu[j]) * rs[j] * g + bta;
      int byte = (r << 9) + (col << 1);
      byte ^= (r & 7) << 4;
      *(unsigned short*)(smem_c + byte) = f2bf(v);
    }
  }
  __syncthreads();
  // readback: thread t -> row t>>2, 64 channels, cvt fp8, 64B coalesced store
  {
    int r = tid >> 2, cg = (tid & 3) * 64;
    long gr = rowbase + r;
    uint32_t ow[16];
#pragma unroll
    for (int i = 0; i < 8; ++i) {
      int byte = (r << 9) + ((cg + i * 8) << 1);
      byte ^= (r & 7) << 4;
      s16x8 v8 = *(const s16x8*)(smem_c + byte);
      float f0 = bf2f((unsigned short)v8[0]), f1 = bf2f((unsigned short)v8[1]);
      float f2 = bf2f((unsigned short)v8[2]), f3 = bf2f((unsigned short)v8[3]);
      float f4 = bf2f((unsigned short)v8[4]), f5 = bf2f((unsigned short)v8[5]);
      float f6 = bf2f((unsigned short)v8[6]), f7 = bf2f((unsigned short)v8[7]);
      int w0 = __builtin_amdgcn_cvt_pk_fp8_f32(f0, f1, 0, false);
      w0 = __builtin_amdgcn_cvt_pk_fp8_f32(f2, f3, w0, true);
      int w1 = __builtin_amdgcn_cvt_pk_fp8_f32(f4, f5, 0, false);
      w1 = __builtin_amdgcn_cvt_pk_fp8_f32(f6, f7, w1, true);
      ow[i * 2] = (uint32_t)w0; ow[i * 2 + 1] = (uint32_t)w1;
    }
    if (gr < NPTS) {
      uint8_t* dp = h1f8 + gr * GCH + cg;
#pragma unroll
      for (int s = 0; s < 4; ++s) {
        u32x4 q = {ow[s * 4], ow[s * 4 + 1], ow[s * 4 + 2], ow[s * 4 + 3]};
        *(u32x4*)(dp + s * 16) = q;   // normal store: keep h1f8 L3-resident
      }
    }
  }
}

// ---------- K2: depthwise gather on fp8 h1 (128 MB, L3-resident), 4 pts/wave ----------
__global__ __launch_bounds__(256) void k_dw(
    const uint8_t* __restrict__ h1f8, const int* __restrict__ nbr,
    const float* __restrict__ dw_w, const float* __restrict__ dw_b,
    unsigned short* __restrict__ h2) {
  __shared__ float wf[KTAP * 4 * 16 * 4];   // [k][j][l15][4] f32, 27648 B, conflict-free
  __shared__ int idxl[32 * KTAP];           // 3456 B
  int tid = threadIdx.x, lane = tid & 63, wv = tid >> 6;
  int l15 = lane & 15, q = lane >> 4;

  for (int u = tid; u < KTAP * 64; u += 256) {   // stage weights f32
    int g = u >> 4, ld = u & 15, k = g >> 2, j = g & 3;
    f32x4 w4 = *(const f32x4*)(dw_w + k * GCH + ld * 16 + j * 4);
    *(f32x4*)&wf[u * 4] = w4;
  }
  size_t pblk = (size_t)blockIdx.x * 32;
  for (int i = tid; i < 32 * KTAP; i += 256)     // stage indices
    idxl[i] = nbr[pblk * KTAP + i];
  __syncthreads();

  f32x2 bias[8];
#pragma unroll
  for (int d = 0; d < 4; ++d) {
    f32x4 b4 = *(const f32x4*)(dw_b + l15 * 16 + d * 4);
    bias[2 * d]     = (f32x2){b4[0], b4[1]};
    bias[2 * d + 1] = (f32x2){b4[2], b4[3]};
  }
  int coff = l15 * 16;   // byte offset in 256-B fp8 row

#pragma unroll
  for (int it = 0; it < 2; ++it) {
    int pl = it * 16 + wv * 4 + q;
    f32x2 acc[8];
#pragma unroll
    for (int i = 0; i < 8; ++i) acc[i] = bias[i];
#pragma unroll
    for (int k = 0; k < KTAP; ++k) {
      int row = idxl[pl * KTAP + k];                       // LDS broadcast per 16-lane group
      const uint8_t* sp = h1f8 + ((size_t)(uint32_t)row << 8) + coff;
      u32x4 hv = *(const u32x4*)sp;                        // 16 fp8 channels
#pragma unroll
      for (int j = 0; j < 4; ++j) {
        f32x4 w4 = *(const f32x4*)&wf[((k * 4 + j) * 16 + l15) * 4];
        f32x2 lo = __builtin_amdgcn_cvt_pk_f32_fp8(hv[j], false);
        f32x2 hi = __builtin_amdgcn_cvt_pk_f32_fp8(hv[j], true);
        acc[2 * j]     += lo * (f32x2){w4[0], w4[1]};
        acc[2 * j + 1] += hi * (f32x2){w4[2], w4[3]};
      }
    }
    size_t p = pblk + pl;
    u32x4 o0, o1;
#pragma unroll
    for (int d = 0; d < 4; ++d) {
      o0[d] = (uint32_t)f2bf(acc[d][0]) | ((uint32_t)f2bf(acc[d][1]) << 16);
      o1[d] = (uint32_t)f2bf(acc[4 + d][0]) | ((uint32_t)f2bf(acc[4 + d][1]) << 16);
    }
    unsigned short* op = h2 + p * GCH + l15 * 16;
    __builtin_nontemporal_store(o0, (u32x4*)op);
    __builtin_nontemporal_store(o1, (u32x4*)(op + 8));
  }
}

// ---------- K4: h3 = gelu(h2 @ W2 + b2) bf16, + per-channel sum(h3^2) ----------
__global__ __launch_bounds__(512) void k_gemm2(
    const unsigned short* __restrict__ h2, const unsigned short* __restrict__ W2t,
    const float* __restrict__ b2, unsigned short* __restrict__ h3,
    float* __restrict__ sums) {
  __shared__ unsigned short Al[128][GCH + 8];
  __shared__ unsigned short Bl[COUT * GCH];
  __shared__ float ssum[COUT];
  int tid = threadIdx.x, lane = tid & 63, wv = tid >> 6;
  int l15 = lane & 15, l4 = lane >> 4;
  long rowbase = (long)blockIdx.x * 128;
  if (tid < COUT) ssum[tid] = 0.f;
#pragma unroll
  for (int i = 0; i < 8; ++i) {
    int off = (i * 512 + tid) * 8;
    *(s16x8*)&Bl[off] = *(const s16x8*)&W2t[off];
  }
  {
    int ar = tid >> 2, ac = (tid & 3) * 64;
    long gr = rowbase + ar;
    const unsigned short* sp = h2 + gr * GCH + ac;
    bool ok = gr < NPTS;
    s16x8 zs = {0, 0, 0, 0, 0, 0, 0, 0};
#pragma unroll
    for (int u = 0; u < 8; ++u) {
      s16x8 v = zs;
      if (ok) v = __builtin_nontemporal_load((const s16x8*)(sp + u * 8));
      *(s16x8*)&Al[ar][ac + u * 8] = v;
    }
  }
  __syncthreads();

  f32x4 acc[8];
#pragma unroll
  for (int f = 0; f < 8; ++f) acc[f] = (f32x4){0.f, 0.f, 0.f, 0.f};
  s16x8 a[8];
#pragma unroll
  for (int s = 0; s < 8; ++s)
    a[s] = *(const s16x8*)&Al[wv * 16 + l15][s * 32 + l4 * 8];
#pragma unroll
  for (int f = 0; f < 8; ++f)
#pragma unroll
    for (int s = 0; s < 8; ++s) {
      s16x8 bfr = *(const s16x8*)&Bl[((f * 8 + s) * 64 + lane) * 8];
      acc[f] = __builtin_amdgcn_mfma_f32_16x16x32_bf16(a[s], bfr, acc[f], 0, 0, 0);
    }
#pragma unroll
  for (int f = 0; f < 8; ++f) {
    int col = f * 16 + l15;
    float bb = b2[col];
    float ps = 0.f;
#pragma unroll
    for (int j = 0; j < 4; ++j) {
      long r = rowbase + wv * 16 + l4 * 4 + j;
      float v = acc[f][j] + bb;
      float g = 0.5f * v * (1.f + erff(v * 0.70710678118654752f));
      if (r < NPTS) {
        h3[r * COUT + col] = f2bf(g);
        ps += g * g;
      }
    }
    ps += __shfl_xor(ps, 16);
    ps += __shfl_xor(ps, 32);
    if (l4 == 0) atomicAdd(&ssum[col], ps);
  }
  __syncthreads();
  if (tid < COUT) atomicAdd(&sums[tid], ssum[tid]);
}

// ---------- K5: GRN finalize -> scale/shift tables ----------
__global__ void k_grn(const float* __restrict__ sums, const float* __restrict__ grn_g,
                      const float* __restrict__ grn_b, float* __restrict__ sAB) {
  __shared__ float gx[COUT];
  __shared__ float mean_s;
  int t = threadIdx.x;
  float g = sqrtf(sums[t]);
  gx[t] = g;
  __syncthreads();
  if (t == 0) {
    float s = 0.f;
    for (int i = 0; i < COUT; ++i) s += gx[i];
    mean_s = s * (1.f / COUT);
  }
  __syncthreads();
  float nx = g / (mean_s + 1e-6f);
  sAB[t] = grn_g[t] * nx + 1.f;
  sAB[COUT + t] = grn_b[t];
}

// ---------- K6: out = h3*sA + sB + x ----------
__global__ __launch_bounds__(256) void k_final(
    const unsigned short* __restrict__ h3, const float* __restrict__ x,
    const float* __restrict__ sAB, float* __restrict__ out) {
  long q = (long)blockIdx.x * 256 + threadIdx.x;
  long idx = q * 4;
  int c0 = (int)(idx & (COUT - 1));
  f32x4 sA = *(const f32x4*)(sAB + c0);
  f32x4 sB = *(const f32x4*)(sAB + COUT + c0);
  ushort4 hv = *(const ushort4*)(h3 + idx);
  f32x4 xv = __builtin_nontemporal_load((const f32x4*)(x + idx));
  f32x4 r;
  r[0] = bf2f(hv.x) * sA[0] + sB[0] + xv[0];
  r[1] = bf2f(hv.y) * sA[1] + sB[1] + xv[1];
  r[2] = bf2f(hv.z) * sA[2] + sB[2] + xv[2];
  r[3] = bf2f(hv.w) * sA[3] + sB[3] + xv[3];
  __builtin_nontemporal_store(r, (f32x4*)(out + idx));
}

extern "C" void kernel_launch(void* const* d_in, const int* in_sizes, int n_in,
                              void* d_out, int out_size, void* d_ws, size_t ws_size,
                              hipStream_t stream) {
  const float* x     = (const float*)d_in[0];
  const int*   nbr   = (const int*)d_in[1];
  const float* W1    = (const float*)d_in[2];
  const float* b1    = (const float*)d_in[3];
  const float* ln_g  = (const float*)d_in[4];
  const float* ln_b  = (const float*)d_in[5];
  const float* dw_w  = (const float*)d_in[6];
  const float* dw_b  = (const float*)d_in[7];
  const float* W2    = (const float*)d_in[8];
  const float* b2    = (const float*)d_in[9];
  const float* grn_g = (const float*)d_in[10];
  const float* grn_b = (const float*)d_in[11];
  float* out = (float*)d_out;

  char* ws = (char*)d_ws;
  uint8_t* h1f8       = (uint8_t*)ws;                        // [N][256] fp8, 128 MB
  unsigned short* h3  = (unsigned short*)(ws + (size_t)NPTS * GCH);  // [N][128] bf16, 128 MB
  size_t off = (size_t)NPTS * GCH * 2;                       // 256 MB
  unsigned short* W1t = (unsigned short*)(ws + off);
  unsigned short* W2t = (unsigned short*)(ws + off + 65536);
  float* sums         = (float*)(ws + off + 131072);
  float* sAB          = (float*)(ws + off + 131072 + 512);
  unsigned short* h2  = (unsigned short*)d_out;              // [N][256] bf16 aliases d_out

  k_prep<<<32, 256, 0, stream>>>(W1, W2, W1t, W2t, sums);
  k_gemm1_ln<<<(NPTS + 127) / 128, 512, 0, stream>>>(x, W1t, b1, ln_g, ln_b, h1f8);
  k_dw<<<NPTS / 32, 256, 0, stream>>>(h1f8, nbr, dw_w, dw_b, h2);
  k_gemm2<<<(NPTS + 127) / 128, 512, 0, stream>>>(h2, W2t, b2, h3, sums);
  k_grn<<<1, COUT, 0, stream>>>(sums, grn_g, grn_b, sAB);
  k_final<<<(NPTS * COUT / 4) / 256, 256, 0, stream>>>(h3, x, sAB, out);
}